// Round 10
// baseline (97.456 us; speedup 1.0000x reference)
//
#include <hip/hip_runtime.h>
#include <cstdint>

#define BB 8
#define PP 4096
#define DD 256
#define CC 1024

#define TM 128
#define TN 64

#define XT_BYTES (33554432ull)   // 8*32 tiles * 128KB
#define WT_BYTES (1048576ull)    // 8 chunks * 128KB
#define TILE_BYTES 131072ull     // one (b,pt) or 128-col W chunk

typedef _Float16 f16x8 __attribute__((ext_vector_type(8)));
typedef float f32x16 __attribute__((ext_vector_type(16)));
typedef unsigned long long u64;

// ---------------------------------------------------------------------------
// init argmax cells (fallback path only): score 0.0 @ p=0
// ---------------------------------------------------------------------------
__global__ __launch_bounds__(256) void init_ws_kernel(u64* keys, int n) {
    int i = blockIdx.x * 256 + threadIdx.x;
    if (i < n) keys[i] = 0x00000000FFFFFFFFull;
}

// ---------------------------------------------------------------------------
// transform: fp32 [rows][256] -> fragment-ordered fp16 hi/lo planes.
// Output chunk (k16,rt,sp,slot) of 16B at ((k16*4+rt)*2+sp)*1024 + slot*16,
// slot = (row&31) + 32*ksub; k16 = k/16 in 0..15. Each 1KB chunk is exactly
// one wave fragment (lane -> slot) of mfma_32x32x16.
// Blocks 0..31 additionally init the 8192 argmax key cells (fused init).
// grid = 528: ids 0..511 -> x tile (id>>1), h=id&1; 512..527 -> W chunk.
// ---------------------------------------------------------------------------
__global__ __launch_bounds__(256) void transform_kernel(
    const float* __restrict__ x, const float* __restrict__ W,
    char* __restrict__ xT, char* __restrict__ wT, u64* __restrict__ keys)
{
    __shared__ float ls[64 * 260];   // 64 rows, stride 260 (pad: f4-aligned)

    const int id = blockIdx.x;
    const int t = threadIdx.x;
    if (id < 32) keys[id * 256 + t] = 0x00000000FFFFFFFFull;

    const int tile = id >> 1;
    const int h = id & 1;
    const float* src;
    char* dstTile;
    if (tile < 256) {
        src = x + (size_t)tile * 128 * 256;          // tile = b*32+pt
        dstTile = xT + (size_t)tile * TILE_BYTES;
    } else {
        int cy = tile - 256;
        src = W + (size_t)cy * 128 * 256;
        dstTile = wT + (size_t)cy * TILE_BYTES;
    }

    // load 64 rows x 256 k, coalesced
    #pragma unroll
    for (int i = 0; i < 16; ++i) {
        int c = i * 256 + t;              // 0..4095
        int row = c >> 6, kq = c & 63;
        float4 v = *reinterpret_cast<const float4*>(
            src + ((size_t)(h * 64 + row)) * 256 + kq * 4);
        *reinterpret_cast<float4*>(&ls[row * 260 + kq * 4]) = v;
    }
    __syncthreads();

    // emit 4096 16B chunks, coalesced (slot fastest)
    #pragma unroll
    for (int j = 0; j < 16; ++j) {
        int q = j * 256 + t;              // 0..4095
        int slot = q & 63;
        int sp = (q >> 6) & 1;
        int rtl = (q >> 7) & 1;
        int k16 = q >> 8;                 // 0..15
        int rowl = rtl * 32 + (slot & 31);
        int k = k16 * 16 + (slot >> 5) * 8;
        const float* p = &ls[rowl * 260 + k];
        f16x8 o;
        if (sp == 0) {
            #pragma unroll
            for (int i = 0; i < 8; ++i) o[i] = (_Float16)p[i];
        } else {
            #pragma unroll
            for (int i = 0; i < 8; ++i) {
                _Float16 hv = (_Float16)p[i];
                o[i] = (_Float16)((p[i] - (float)hv) * 4096.0f);
            }
        }
        int rt = h * 2 + rtl;
        size_t off = (((size_t)k16 * 4 + rt) * 2 + sp) * 1024 + (size_t)slot * 16;
        *reinterpret_cast<f16x8*>(dstTile + off) = o;
    }
}

// ---------------------------------------------------------------------------
// main GEMM: fp16-split MFMA (scores = relu(x @ W^T)) + per-column argmax.
// r10 OCCUPANCY EXPERIMENT: r9's direct-streaming structure, but per-block
// tile 128x64 (4 waves of 64x32): acc = 64 VGPR (vs 128) -> 3 waves/SIMD
// under launch_bounds(256,3) (cap 170 regs, est ~135, headroom vs r7 spill).
// A/B vs r9 isolates occupancy-vs-bytes: +50% waves, +50% L2 traffic.
// ---------------------------------------------------------------------------
__global__ __launch_bounds__(256, 3) void gemm_argmax_s_kernel(
    const char* __restrict__ xT, const char* __restrict__ wT,
    u64* __restrict__ keys)
{
    __shared__ u64 smax[TN];

    const int tid = threadIdx.x;
    const int lane = tid & 63;
    const int w = tid >> 6;
    const int wy = w >> 1, wx = w & 1;   // 2x2 waves, each 64 rows x 32 cols
    const int pt = blockIdx.x;           // 0..31
    const int cy = blockIdx.y;           // 0..15 (64-col groups)
    const int b  = blockIdx.z;
    const int p0 = pt * TM;
    const int c0 = cy * TN;

    // per-lane fragment bases; B: 128-col chunk cy>>1, col-group within chunk
    const char* aBase = xT + ((size_t)(b * 32 + pt)) * TILE_BYTES + (size_t)lane * 16;
    const int cg = (cy & 1) * 2 + wx;    // 32-col group 0..3 within chunk
    const char* bBase = wT + (size_t)(cy >> 1) * TILE_BYTES + (size_t)lane * 16;

    #define AFRAG(st, rt, sp) \
        (*reinterpret_cast<const f16x8*>(aBase + ((((st) * 4 + (wy * 2 + (rt))) * 2 + (sp)) << 10)))
    #define BFRAG(st, sp) \
        (*reinterpret_cast<const f16x8*>(bBase + ((((st) * 4 + cg) * 2 + (sp)) << 10)))

    f32x16 zero;
    #pragma unroll
    for (int i = 0; i < 16; ++i) zero[i] = 0.f;
    f32x16 acc_hi[2], acc_lo[2];
    #pragma unroll
    for (int i = 0; i < 2; ++i) { acc_hi[i] = zero; acc_lo[i] = zero; }

    // two named fragment sets (static indexing; depth-2 pipeline)
    f16x8 a0[2][2], b0v[2], a1[2][2], b1v[2];

    #define LOADSET(AS, BS, st)                                   \
        do {                                                      \
            _Pragma("unroll")                                     \
            for (int rt = 0; rt < 2; ++rt) {                      \
                AS[rt][0] = AFRAG(st, rt, 0);                     \
                AS[rt][1] = AFRAG(st, rt, 1);                     \
            }                                                     \
            BS[0] = BFRAG(st, 0);                                 \
            BS[1] = BFRAG(st, 1);                                 \
        } while (0)

    #define COMPUTE(AS, BS)                                                     \
        do {                                                                    \
            _Pragma("unroll")                                                   \
            for (int rt = 0; rt < 2; ++rt) {                                    \
                acc_hi[rt] = __builtin_amdgcn_mfma_f32_32x32x16_f16(            \
                    AS[rt][0], BS[0], acc_hi[rt], 0, 0, 0);                     \
                acc_lo[rt] = __builtin_amdgcn_mfma_f32_32x32x16_f16(            \
                    AS[rt][0], BS[1], acc_lo[rt], 0, 0, 0);                     \
                acc_lo[rt] = __builtin_amdgcn_mfma_f32_32x32x16_f16(            \
                    AS[rt][1], BS[0], acc_lo[rt], 0, 0, 0);                     \
            }                                                                   \
        } while (0)

    LOADSET(a0, b0v, 0);
    LOADSET(a1, b1v, 1);

    #pragma unroll
    for (int st = 0; st < 16; st += 2) {
        COMPUTE(a0, b0v);
        if (st + 2 < 16) LOADSET(a0, b0v, st + 2);
        COMPUTE(a1, b1v);
        if (st + 3 < 16) LOADSET(a1, b1v, st + 3);
    }

    #undef LOADSET
    #undef COMPUTE
    #undef AFRAG
    #undef BFRAG

    // ---- epilogue: per-column argmax over this block's 128 rows ----
    if (tid < TN) smax[tid] = 0ull;
    __syncthreads();

    {
        u64 bk = 0ull;
        #pragma unroll
        for (int rt = 0; rt < 2; ++rt) {
            f32x16 h = acc_hi[rt];
            f32x16 l = acc_lo[rt];
            #pragma unroll
            for (int reg = 0; reg < 16; ++reg) {
                float v = fmaxf(h[reg] + l[reg] * (1.0f / 4096.0f), 0.f);
                int prow = p0 + (wy * 2 + rt) * 32 +
                           (reg & 3) + 8 * (reg >> 2) + 4 * (lane >> 5);
                u64 key = ((u64)__float_as_uint(v) << 32) |
                          (unsigned int)(0xFFFFFFFFu - (unsigned int)prow);
                bk = bk > key ? bk : key;
            }
        }
        u64 other = __shfl_xor(bk, 32, 64);
        bk = bk > other ? bk : other;
        if (lane < 32) {
            int col = wx * 32 + (lane & 31);
            atomicMax(&smax[col], bk);
        }
    }
    __syncthreads();
    if (tid < TN) {
        atomicMax(&keys[(size_t)b * CC + c0 + tid], smax[tid]);
    }
}

// ---------------------------------------------------------------------------
// fallback (ws too small): in-kernel conversion version (round-2, verified)
// ---------------------------------------------------------------------------
__global__ __launch_bounds__(256, 2) void gemm_argmax_conv_kernel(
    const float* __restrict__ x, const float* __restrict__ W,
    u64* __restrict__ keys)
{
    __shared__ f16x8 lA[4][4][2][64];
    __shared__ f16x8 lB[4][4][2][64];

    const int tid = threadIdx.x;
    const int lane = tid & 63;
    const int w = tid >> 6;
    const int wy = w >> 1, wx = w & 1;
    const int p0 = blockIdx.x * 128;
    const int c0 = blockIdx.y * 128;
    const int b  = blockIdx.z;

    const float* xb = x + (size_t)b * PP * DD;

    f32x16 zero;
    #pragma unroll
    for (int i = 0; i < 16; ++i) zero[i] = 0.f;
    f32x16 acc_hi[2][2], acc_lo[2][2];
    #pragma unroll
    for (int i = 0; i < 2; ++i)
        #pragma unroll
        for (int j = 0; j < 2; ++j) { acc_hi[i][j] = zero; acc_lo[i][j] = zero; }

    for (int st = 0; st < 4; ++st) {
        const int k0 = st * 64;
        float4 gA[8], gB[8];
        #pragma unroll
        for (int v = 0; v < 4; ++v) {
            int pi = tid + 256 * v;
            int r  = pi >> 3;
            int ck = (pi & 7) * 8;
            const float* pa = xb + (size_t)(p0 + r) * DD + k0 + ck;
            gA[2 * v]     = *reinterpret_cast<const float4*>(pa);
            gA[2 * v + 1] = *reinterpret_cast<const float4*>(pa + 4);
            const float* pb = W + (size_t)(c0 + r) * DD + k0 + ck;
            gB[2 * v]     = *reinterpret_cast<const float4*>(pb);
            gB[2 * v + 1] = *reinterpret_cast<const float4*>(pb + 4);
        }
        __syncthreads();
        #pragma unroll
        for (int v = 0; v < 4; ++v) {
            int pi = tid + 256 * v;
            int r  = pi >> 3;
            int ph = pi & 7;
            int kk = ph >> 1;
            int half = ph & 1;
            int slot = (r & 31) + 32 * half;
            int rtp = r >> 5;
            float va[8] = {gA[2*v].x, gA[2*v].y, gA[2*v].z, gA[2*v].w,
                           gA[2*v+1].x, gA[2*v+1].y, gA[2*v+1].z, gA[2*v+1].w};
            f16x8 h1, h2;
            #pragma unroll
            for (int i = 0; i < 8; ++i) {
                _Float16 h = (_Float16)va[i];
                h1[i] = h;
                h2[i] = (_Float16)((va[i] - (float)h) * 4096.0f);
            }
            lA[kk][rtp][0][slot] = h1;
            lA[kk][rtp][1][slot] = h2;
            float vb[8] = {gB[2*v].x, gB[2*v].y, gB[2*v].z, gB[2*v].w,
                           gB[2*v+1].x, gB[2*v+1].y, gB[2*v+1].z, gB[2*v+1].w};
            f16x8 g1, g2;
            #pragma unroll
            for (int i = 0; i < 8; ++i) {
                _Float16 h = (_Float16)vb[i];
                g1[i] = h;
                g2[i] = (_Float16)((vb[i] - (float)h) * 4096.0f);
            }
            lB[kk][rtp][0][slot] = g1;
            lB[kk][rtp][1][slot] = g2;
        }
        __syncthreads();
        #pragma unroll
        for (int kk = 0; kk < 4; ++kk) {
            f16x8 xa[2][2], wb2[2][2];
            #pragma unroll
            for (int rt = 0; rt < 2; ++rt) {
                xa[rt][0] = lA[kk][wy * 2 + rt][0][lane];
                xa[rt][1] = lA[kk][wy * 2 + rt][1][lane];
            }
            #pragma unroll
            for (int ct = 0; ct < 2; ++ct) {
                wb2[ct][0] = lB[kk][wx * 2 + ct][0][lane];
                wb2[ct][1] = lB[kk][wx * 2 + ct][1][lane];
            }
            #pragma unroll
            for (int rt = 0; rt < 2; ++rt)
                #pragma unroll
                for (int ct = 0; ct < 2; ++ct) {
                    acc_hi[rt][ct] = __builtin_amdgcn_mfma_f32_32x32x16_f16(
                        xa[rt][0], wb2[ct][0], acc_hi[rt][ct], 0, 0, 0);
                    acc_lo[rt][ct] = __builtin_amdgcn_mfma_f32_32x32x16_f16(
                        xa[rt][0], wb2[ct][1], acc_lo[rt][ct], 0, 0, 0);
                    acc_lo[rt][ct] = __builtin_amdgcn_mfma_f32_32x32x16_f16(
                        xa[rt][1], wb2[ct][0], acc_lo[rt][ct], 0, 0, 0);
                }
        }
    }

    u64* smax = reinterpret_cast<u64*>(&lA[0][0][0][0]);
    __syncthreads();
    if (tid < 128) smax[tid] = 0ull;
    __syncthreads();

    #pragma unroll
    for (int ct = 0; ct < 2; ++ct) {
        u64 bk = 0ull;
        #pragma unroll
        for (int rt = 0; rt < 2; ++rt) {
            f32x16 h = acc_hi[rt][ct];
            f32x16 l = acc_lo[rt][ct];
            #pragma unroll
            for (int reg = 0; reg < 16; ++reg) {
                float v = fmaxf(h[reg] + l[reg] * (1.0f / 4096.0f), 0.f);
                int prow = p0 + (wy * 2 + rt) * 32 +
                           (reg & 3) + 8 * (reg >> 2) + 4 * (lane >> 5);
                u64 key = ((u64)__float_as_uint(v) << 32) |
                          (unsigned int)(0xFFFFFFFFu - (unsigned int)prow);
                bk = bk > key ? bk : key;
            }
        }
        u64 other = __shfl_xor(bk, 32, 64);
        bk = bk > other ? bk : other;
        if (lane < 32) {
            int col = (wx * 2 + ct) * 32 + (lane & 31);
            atomicMax(&smax[col], bk);
        }
    }
    __syncthreads();
    if (tid < 128) {
        atomicMax(&keys[(size_t)b * CC + c0 + tid], smax[tid]);
    }
}

// ---------------------------------------------------------------------------
// scatter: out[b, argmax_p(b,c), :] += W[c, :]
// ---------------------------------------------------------------------------
__global__ __launch_bounds__(64) void scatter_kernel(
    const u64* __restrict__ keys,
    const float* __restrict__ W,
    float* __restrict__ out)
{
    const int cell = blockIdx.x;
    const int c = cell & (CC - 1);
    const int b = cell >> 10;
    u64 key = keys[cell];
    unsigned int p = (0xFFFFFFFFu - (unsigned int)(key & 0xFFFFFFFFull)) & (PP - 1);

    const float* wrow = W + (size_t)c * DD;
    float* orow = out + ((size_t)b * PP + p) * DD;
    const int t = threadIdx.x;
    #pragma unroll
    for (int u = 0; u < 4; u++) {
        int idx = u * 64 + t;
        atomicAdd(&orow[idx], wrow[idx]);
    }
}

extern "C" void kernel_launch(void* const* d_in, const int* in_sizes, int n_in,
                              void* d_out, int out_size, void* d_ws, size_t ws_size,
                              hipStream_t stream) {
    const float* x = (const float*)d_in[0];   // [B, P, D] fp32
    const float* W = (const float*)d_in[1];   // [C, D]    fp32
    float* out = (float*)d_out;

    char* wsb = (char*)d_ws;
    u64* keys = (u64*)wsb;                          // 64 KB
    char* xT = wsb + 65536;
    char* wT = xT + XT_BYTES;
    const size_t need = 65536 + XT_BYTES + WT_BYTES;

    hipMemsetAsync(d_out, 0, (size_t)out_size * sizeof(float), stream);

    if (ws_size >= need) {
        transform_kernel<<<528, 256, 0, stream>>>(x, W, xT, wT, keys);
        dim3 grid(PP / TM, CC / TN, BB);
        gemm_argmax_s_kernel<<<grid, 256, 0, stream>>>(xT, wT, keys);
    } else {
        int n = BB * CC;
        init_ws_kernel<<<(n + 255) / 256, 256, 0, stream>>>(keys, n);
        dim3 grid(PP / 128, CC / 128, BB);
        gemm_argmax_conv_kernel<<<grid, 256, 0, stream>>>(x, W, keys);
    }

    {
        dim3 grid(BB * CC);
        scatter_kernel<<<grid, 64, 0, stream>>>(keys, W, out);
    }
}

// Round 11
// 90.748 us; speedup vs baseline: 1.0739x; 1.0739x over previous
//
#include <hip/hip_runtime.h>
#include <cstdint>

#define BB 8
#define PP 4096
#define DD 256
#define CC 1024

#define TM 128
#define TN 128

#define XT_BYTES (33554432ull)   // 8*32 tiles * 128KB
#define WT_BYTES (1048576ull)    // 8 chunks * 128KB
#define TILE_BYTES 131072ull     // one (b,pt) or cy chunk: 128 rows x 256 k x 2 planes x 2B

typedef _Float16 f16x8 __attribute__((ext_vector_type(8)));
typedef float f32x16 __attribute__((ext_vector_type(16)));
typedef unsigned long long u64;

// ---------------------------------------------------------------------------
// init argmax cells (fallback path only): score 0.0 @ p=0
// ---------------------------------------------------------------------------
__global__ __launch_bounds__(256) void init_ws_kernel(u64* keys, int n) {
    int i = blockIdx.x * 256 + threadIdx.x;
    if (i < n) keys[i] = 0x00000000FFFFFFFFull;
}

// ---------------------------------------------------------------------------
// transform: fp32 [rows][256] -> fragment-ordered fp16 hi/lo planes.
// Output chunk (k16,rt,sp,slot) of 16B at ((k16*4+rt)*2+sp)*1024 + slot*16,
// slot = (row&31) + 32*ksub; k16 = k/16 in 0..15. Each 1KB chunk is exactly
// one wave fragment (lane -> slot) of mfma_32x32x16.
// Blocks 0..31 additionally init the 8192 argmax key cells (fused init).
// grid = 528: ids 0..511 -> x tile (id>>1), h=id&1; 512..527 -> W chunk.
// ---------------------------------------------------------------------------
__global__ __launch_bounds__(256) void transform_kernel(
    const float* __restrict__ x, const float* __restrict__ W,
    char* __restrict__ xT, char* __restrict__ wT, u64* __restrict__ keys)
{
    __shared__ float ls[64 * 260];   // 64 rows, stride 260 (pad: f4-aligned)

    const int id = blockIdx.x;
    const int t = threadIdx.x;
    if (id < 32) keys[id * 256 + t] = 0x00000000FFFFFFFFull;

    const int tile = id >> 1;
    const int h = id & 1;
    const float* src;
    char* dstTile;
    if (tile < 256) {
        src = x + (size_t)tile * 128 * 256;          // tile = b*32+pt
        dstTile = xT + (size_t)tile * TILE_BYTES;
    } else {
        int cy = tile - 256;
        src = W + (size_t)cy * 128 * 256;
        dstTile = wT + (size_t)cy * TILE_BYTES;
    }

    // load 64 rows x 256 k, coalesced
    #pragma unroll
    for (int i = 0; i < 16; ++i) {
        int c = i * 256 + t;              // 0..4095
        int row = c >> 6, kq = c & 63;
        float4 v = *reinterpret_cast<const float4*>(
            src + ((size_t)(h * 64 + row)) * 256 + kq * 4);
        *reinterpret_cast<float4*>(&ls[row * 260 + kq * 4]) = v;
    }
    __syncthreads();

    // emit 4096 16B chunks, coalesced (slot fastest)
    #pragma unroll
    for (int j = 0; j < 16; ++j) {
        int q = j * 256 + t;              // 0..4095
        int slot = q & 63;
        int sp = (q >> 6) & 1;
        int rtl = (q >> 7) & 1;
        int k16 = q >> 8;                 // 0..15
        int rowl = rtl * 32 + (slot & 31);
        int k = k16 * 16 + (slot >> 5) * 8;
        const float* p = &ls[rowl * 260 + k];
        f16x8 o;
        if (sp == 0) {
            #pragma unroll
            for (int i = 0; i < 8; ++i) o[i] = (_Float16)p[i];
        } else {
            #pragma unroll
            for (int i = 0; i < 8; ++i) {
                _Float16 hv = (_Float16)p[i];
                o[i] = (_Float16)((p[i] - (float)hv) * 4096.0f);
            }
        }
        int rt = h * 2 + rtl;
        size_t off = (((size_t)k16 * 4 + rt) * 2 + sp) * 1024 + (size_t)slot * 16;
        *reinterpret_cast<f16x8*>(dstTile + off) = o;
    }
}

// ---------------------------------------------------------------------------
// main GEMM: fp16-split MFMA (scores = relu(x @ W^T)) + per-column argmax.
// r11: r9's direct-streaming 128x128 structure, pipeline deepened to 3
// (3 named fragment sets, fully-unrolled 16-step schedule, compile-time
// indices). Cover between issue and consume = 2 COMPUTEs (~24 MFMA) which
// exceeds the loaded L2 service latency — the isolated invariant across
// r4/r5/r8/r9 (all depth~2, all 63us). Regs: acc 128 + 3x32 frags ~ 240
// at (256,2); spill signature = VGPR 256 + WRITE_SIZE blowup (r7).
// ---------------------------------------------------------------------------
__global__ __launch_bounds__(256, 2) void gemm_argmax_s_kernel(
    const char* __restrict__ xT, const char* __restrict__ wT,
    u64* __restrict__ keys)
{
    __shared__ u64 smax[TN];

    const int tid = threadIdx.x;
    const int lane = tid & 63;
    const int w = tid >> 6;
    const int wy = w >> 1, wx = w & 1;
    const int pt = blockIdx.x;
    const int cy = blockIdx.y;
    const int b  = blockIdx.z;
    const int p0 = pt * TM;
    const int c0 = cy * TN;

    // per-lane fragment bases
    const char* aBase = xT + ((size_t)(b * 32 + pt)) * TILE_BYTES + (size_t)lane * 16;
    const char* bBase = wT + (size_t)cy * TILE_BYTES + (size_t)lane * 16;

    #define AFRAG(st, rt, sp) \
        (*reinterpret_cast<const f16x8*>(aBase + ((((st) * 4 + (wy * 2 + (rt))) * 2 + (sp)) << 10)))
    #define BFRAG(st, ct, sp) \
        (*reinterpret_cast<const f16x8*>(bBase + ((((st) * 4 + (wx * 2 + (ct))) * 2 + (sp)) << 10)))

    f32x16 zero;
    #pragma unroll
    for (int i = 0; i < 16; ++i) zero[i] = 0.f;
    f32x16 acc_hi[2][2], acc_lo[2][2];
    #pragma unroll
    for (int i = 0; i < 2; ++i)
        #pragma unroll
        for (int j = 0; j < 2; ++j) { acc_hi[i][j] = zero; acc_lo[i][j] = zero; }

    // three named fragment sets (static indexing; depth-3 pipeline)
    f16x8 a0[2][2], b0v[2][2], a1[2][2], b1v[2][2], a2[2][2], b2v[2][2];

    #define LOADSET(AS, BS, st)                                   \
        do {                                                      \
            _Pragma("unroll")                                     \
            for (int rt = 0; rt < 2; ++rt) {                      \
                AS[rt][0] = AFRAG(st, rt, 0);                     \
                AS[rt][1] = AFRAG(st, rt, 1);                     \
            }                                                     \
            _Pragma("unroll")                                     \
            for (int ct = 0; ct < 2; ++ct) {                      \
                BS[ct][0] = BFRAG(st, ct, 0);                     \
                BS[ct][1] = BFRAG(st, ct, 1);                     \
            }                                                     \
        } while (0)

    #define COMPUTE(AS, BS)                                                     \
        do {                                                                    \
            _Pragma("unroll")                                                   \
            for (int rt = 0; rt < 2; ++rt)                                      \
                _Pragma("unroll")                                               \
                for (int ct = 0; ct < 2; ++ct) {                                \
                    acc_hi[rt][ct] = __builtin_amdgcn_mfma_f32_32x32x16_f16(    \
                        AS[rt][0], BS[ct][0], acc_hi[rt][ct], 0, 0, 0);         \
                    acc_lo[rt][ct] = __builtin_amdgcn_mfma_f32_32x32x16_f16(    \
                        AS[rt][0], BS[ct][1], acc_lo[rt][ct], 0, 0, 0);         \
                    acc_lo[rt][ct] = __builtin_amdgcn_mfma_f32_32x32x16_f16(    \
                        AS[rt][1], BS[ct][0], acc_lo[rt][ct], 0, 0, 0);         \
                }                                                               \
        } while (0)

    // STEP(st, set): consume set (loaded with stage st), refill it with st+3
    #define STEP(st, AS, BS)                                      \
        do {                                                      \
            COMPUTE(AS, BS);                                      \
            if ((st) + 3 < 16) LOADSET(AS, BS, (st) + 3);         \
        } while (0)

    LOADSET(a0, b0v, 0);
    LOADSET(a1, b1v, 1);
    LOADSET(a2, b2v, 2);

    STEP(0,  a0, b0v);  STEP(1,  a1, b1v);  STEP(2,  a2, b2v);
    STEP(3,  a0, b0v);  STEP(4,  a1, b1v);  STEP(5,  a2, b2v);
    STEP(6,  a0, b0v);  STEP(7,  a1, b1v);  STEP(8,  a2, b2v);
    STEP(9,  a0, b0v);  STEP(10, a1, b1v);  STEP(11, a2, b2v);
    STEP(12, a0, b0v);  STEP(13, a1, b1v);  STEP(14, a2, b2v);
    STEP(15, a0, b0v);

    #undef STEP
    #undef LOADSET
    #undef COMPUTE
    #undef AFRAG
    #undef BFRAG

    // ---- epilogue: per-column argmax over this block's 128 rows ----
    if (tid < TN) smax[tid] = 0ull;
    __syncthreads();

    #pragma unroll
    for (int ct = 0; ct < 2; ++ct) {
        u64 bk = 0ull;
        #pragma unroll
        for (int rt = 0; rt < 2; ++rt) {
            f32x16 h = acc_hi[rt][ct];
            f32x16 l = acc_lo[rt][ct];
            #pragma unroll
            for (int reg = 0; reg < 16; ++reg) {
                float v = fmaxf(h[reg] + l[reg] * (1.0f / 4096.0f), 0.f);
                int prow = p0 + (wy * 2 + rt) * 32 +
                           (reg & 3) + 8 * (reg >> 2) + 4 * (lane >> 5);
                u64 key = ((u64)__float_as_uint(v) << 32) |
                          (unsigned int)(0xFFFFFFFFu - (unsigned int)prow);
                bk = bk > key ? bk : key;
            }
        }
        u64 other = __shfl_xor(bk, 32, 64);
        bk = bk > other ? bk : other;
        if (lane < 32) {
            int col = (wx * 2 + ct) * 32 + (lane & 31);
            atomicMax(&smax[col], bk);
        }
    }
    __syncthreads();
    if (tid < TN) {
        atomicMax(&keys[(size_t)b * CC + c0 + tid], smax[tid]);
    }
}

// ---------------------------------------------------------------------------
// fallback (ws too small): in-kernel conversion version (round-2, verified)
// ---------------------------------------------------------------------------
__global__ __launch_bounds__(256, 2) void gemm_argmax_conv_kernel(
    const float* __restrict__ x, const float* __restrict__ W,
    u64* __restrict__ keys)
{
    __shared__ f16x8 lA[4][4][2][64];
    __shared__ f16x8 lB[4][4][2][64];

    const int tid = threadIdx.x;
    const int lane = tid & 63;
    const int w = tid >> 6;
    const int wy = w >> 1, wx = w & 1;
    const int p0 = blockIdx.x * 128;
    const int c0 = blockIdx.y * 128;
    const int b  = blockIdx.z;

    const float* xb = x + (size_t)b * PP * DD;

    f32x16 zero;
    #pragma unroll
    for (int i = 0; i < 16; ++i) zero[i] = 0.f;
    f32x16 acc_hi[2][2], acc_lo[2][2];
    #pragma unroll
    for (int i = 0; i < 2; ++i)
        #pragma unroll
        for (int j = 0; j < 2; ++j) { acc_hi[i][j] = zero; acc_lo[i][j] = zero; }

    for (int st = 0; st < 4; ++st) {
        const int k0 = st * 64;
        float4 gA[8], gB[8];
        #pragma unroll
        for (int v = 0; v < 4; ++v) {
            int pi = tid + 256 * v;
            int r  = pi >> 3;
            int ck = (pi & 7) * 8;
            const float* pa = xb + (size_t)(p0 + r) * DD + k0 + ck;
            gA[2 * v]     = *reinterpret_cast<const float4*>(pa);
            gA[2 * v + 1] = *reinterpret_cast<const float4*>(pa + 4);
            const float* pb = W + (size_t)(c0 + r) * DD + k0 + ck;
            gB[2 * v]     = *reinterpret_cast<const float4*>(pb);
            gB[2 * v + 1] = *reinterpret_cast<const float4*>(pb + 4);
        }
        __syncthreads();
        #pragma unroll
        for (int v = 0; v < 4; ++v) {
            int pi = tid + 256 * v;
            int r  = pi >> 3;
            int ph = pi & 7;
            int kk = ph >> 1;
            int half = ph & 1;
            int slot = (r & 31) + 32 * half;
            int rtp = r >> 5;
            float va[8] = {gA[2*v].x, gA[2*v].y, gA[2*v].z, gA[2*v].w,
                           gA[2*v+1].x, gA[2*v+1].y, gA[2*v+1].z, gA[2*v+1].w};
            f16x8 h1, h2;
            #pragma unroll
            for (int i = 0; i < 8; ++i) {
                _Float16 h = (_Float16)va[i];
                h1[i] = h;
                h2[i] = (_Float16)((va[i] - (float)h) * 4096.0f);
            }
            lA[kk][rtp][0][slot] = h1;
            lA[kk][rtp][1][slot] = h2;
            float vb[8] = {gB[2*v].x, gB[2*v].y, gB[2*v].z, gB[2*v].w,
                           gB[2*v+1].x, gB[2*v+1].y, gB[2*v+1].z, gB[2*v+1].w};
            f16x8 g1, g2;
            #pragma unroll
            for (int i = 0; i < 8; ++i) {
                _Float16 h = (_Float16)vb[i];
                g1[i] = h;
                g2[i] = (_Float16)((vb[i] - (float)h) * 4096.0f);
            }
            lB[kk][rtp][0][slot] = g1;
            lB[kk][rtp][1][slot] = g2;
        }
        __syncthreads();
        #pragma unroll
        for (int kk = 0; kk < 4; ++kk) {
            f16x8 xa[2][2], wb2[2][2];
            #pragma unroll
            for (int rt = 0; rt < 2; ++rt) {
                xa[rt][0] = lA[kk][wy * 2 + rt][0][lane];
                xa[rt][1] = lA[kk][wy * 2 + rt][1][lane];
            }
            #pragma unroll
            for (int ct = 0; ct < 2; ++ct) {
                wb2[ct][0] = lB[kk][wx * 2 + ct][0][lane];
                wb2[ct][1] = lB[kk][wx * 2 + ct][1][lane];
            }
            #pragma unroll
            for (int rt = 0; rt < 2; ++rt)
                #pragma unroll
                for (int ct = 0; ct < 2; ++ct) {
                    acc_hi[rt][ct] = __builtin_amdgcn_mfma_f32_32x32x16_f16(
                        xa[rt][0], wb2[ct][0], acc_hi[rt][ct], 0, 0, 0);
                    acc_lo[rt][ct] = __builtin_amdgcn_mfma_f32_32x32x16_f16(
                        xa[rt][0], wb2[ct][1], acc_lo[rt][ct], 0, 0, 0);
                    acc_lo[rt][ct] = __builtin_amdgcn_mfma_f32_32x32x16_f16(
                        xa[rt][1], wb2[ct][0], acc_lo[rt][ct], 0, 0, 0);
                }
        }
    }

    u64* smax = reinterpret_cast<u64*>(&lA[0][0][0][0]);
    __syncthreads();
    if (tid < 128) smax[tid] = 0ull;
    __syncthreads();

    #pragma unroll
    for (int ct = 0; ct < 2; ++ct) {
        u64 bk = 0ull;
        #pragma unroll
        for (int rt = 0; rt < 2; ++rt) {
            f32x16 h = acc_hi[rt][ct];
            f32x16 l = acc_lo[rt][ct];
            #pragma unroll
            for (int reg = 0; reg < 16; ++reg) {
                float v = fmaxf(h[reg] + l[reg] * (1.0f / 4096.0f), 0.f);
                int prow = p0 + (wy * 2 + rt) * 32 +
                           (reg & 3) + 8 * (reg >> 2) + 4 * (lane >> 5);
                u64 key = ((u64)__float_as_uint(v) << 32) |
                          (unsigned int)(0xFFFFFFFFu - (unsigned int)prow);
                bk = bk > key ? bk : key;
            }
        }
        u64 other = __shfl_xor(bk, 32, 64);
        bk = bk > other ? bk : other;
        if (lane < 32) {
            int col = (wx * 2 + ct) * 32 + (lane & 31);
            atomicMax(&smax[col], bk);
        }
    }
    __syncthreads();
    if (tid < 128) {
        atomicMax(&keys[(size_t)b * CC + c0 + tid], smax[tid]);
    }
}

// ---------------------------------------------------------------------------
// scatter: out[b, argmax_p(b,c), :] += W[c, :]
// ---------------------------------------------------------------------------
__global__ __launch_bounds__(64) void scatter_kernel(
    const u64* __restrict__ keys,
    const float* __restrict__ W,
    float* __restrict__ out)
{
    const int cell = blockIdx.x;
    const int c = cell & (CC - 1);
    const int b = cell >> 10;
    u64 key = keys[cell];
    unsigned int p = (0xFFFFFFFFu - (unsigned int)(key & 0xFFFFFFFFull)) & (PP - 1);

    const float* wrow = W + (size_t)c * DD;
    float* orow = out + ((size_t)b * PP + p) * DD;
    const int t = threadIdx.x;
    #pragma unroll
    for (int u = 0; u < 4; u++) {
        int idx = u * 64 + t;
        atomicAdd(&orow[idx], wrow[idx]);
    }
}

extern "C" void kernel_launch(void* const* d_in, const int* in_sizes, int n_in,
                              void* d_out, int out_size, void* d_ws, size_t ws_size,
                              hipStream_t stream) {
    const float* x = (const float*)d_in[0];   // [B, P, D] fp32
    const float* W = (const float*)d_in[1];   // [C, D]    fp32
    float* out = (float*)d_out;

    char* wsb = (char*)d_ws;
    u64* keys = (u64*)wsb;                          // 64 KB
    char* xT = wsb + 65536;
    char* wT = xT + XT_BYTES;
    const size_t need = 65536 + XT_BYTES + WT_BYTES;

    hipMemsetAsync(d_out, 0, (size_t)out_size * sizeof(float), stream);

    if (ws_size >= need) {
        transform_kernel<<<528, 256, 0, stream>>>(x, W, xT, wT, keys);
        dim3 grid(PP / TM, CC / TN, BB);
        gemm_argmax_s_kernel<<<grid, 256, 0, stream>>>(xT, wT, keys);
    } else {
        int n = BB * CC;
        init_ws_kernel<<<(n + 255) / 256, 256, 0, stream>>>(keys, n);
        dim3 grid(PP / 128, CC / 128, BB);
        gemm_argmax_conv_kernel<<<grid, 256, 0, stream>>>(x, W, keys);
    }

    {
        dim3 grid(BB * CC);
        scatter_kernel<<<grid, 64, 0, stream>>>(keys, W, out);
    }
}

// Round 12
// 86.471 us; speedup vs baseline: 1.1270x; 1.0495x over previous
//
#include <hip/hip_runtime.h>
#include <cstdint>

#define BB 8
#define PP 4096
#define DD 256
#define CC 1024

#define XT_BYTES (33554432ull)   // 8*32 tiles * 128KB
#define WT_BYTES (1048576ull)    // 8 chunks * 128KB
#define TILE_BYTES 131072ull     // one 128-row transformed tile (128r x 256k x 2pl x 2B)

typedef _Float16 f16x8 __attribute__((ext_vector_type(8)));
typedef float f32x16 __attribute__((ext_vector_type(16)));
typedef unsigned long long u64;

__device__ __forceinline__ void async_load16(const void* src, void* lds_dst) {
    __builtin_amdgcn_global_load_lds(
        (const __attribute__((address_space(1))) uint32_t*)src,
        (__attribute__((address_space(3))) uint32_t*)lds_dst,
        16, 0, 0);
}

// ---------------------------------------------------------------------------
// init argmax cells (fallback path only): score 0.0 @ p=0
// ---------------------------------------------------------------------------
__global__ __launch_bounds__(256) void init_ws_kernel(u64* keys, int n) {
    int i = blockIdx.x * 256 + threadIdx.x;
    if (i < n) keys[i] = 0x00000000FFFFFFFFull;
}

// ---------------------------------------------------------------------------
// transform: fp32 [rows][256] -> fragment-ordered fp16 hi/lo planes.
// Output chunk (k16,rt,sp,slot) of 16B at ((k16*4+rt)*2+sp)*1024 + slot*16,
// slot = (row&31) + 32*ksub; k16 = k/16 in 0..15. Each 1KB chunk is one wave
// fragment (lane->slot) of mfma_32x32x16. Unchanged since r7 (verified).
// Blocks 0..31 additionally init the 8192 argmax key cells (fused init).
// grid = 528: ids 0..511 -> x tile (id>>1), h=id&1; 512..527 -> W chunk.
// ---------------------------------------------------------------------------
__global__ __launch_bounds__(256) void transform_kernel(
    const float* __restrict__ x, const float* __restrict__ W,
    char* __restrict__ xT, char* __restrict__ wT, u64* __restrict__ keys)
{
    __shared__ float ls[64 * 260];   // 64 rows, stride 260 (pad: f4-aligned)

    const int id = blockIdx.x;
    const int t = threadIdx.x;
    if (id < 32) keys[id * 256 + t] = 0x00000000FFFFFFFFull;

    const int tile = id >> 1;
    const int h = id & 1;
    const float* src;
    char* dstTile;
    if (tile < 256) {
        src = x + (size_t)tile * 128 * 256;          // tile = b*32+pt
        dstTile = xT + (size_t)tile * TILE_BYTES;
    } else {
        int cy = tile - 256;
        src = W + (size_t)cy * 128 * 256;
        dstTile = wT + (size_t)cy * TILE_BYTES;
    }

    #pragma unroll
    for (int i = 0; i < 16; ++i) {
        int c = i * 256 + t;
        int row = c >> 6, kq = c & 63;
        float4 v = *reinterpret_cast<const float4*>(
            src + ((size_t)(h * 64 + row)) * 256 + kq * 4);
        *reinterpret_cast<float4*>(&ls[row * 260 + kq * 4]) = v;
    }
    __syncthreads();

    #pragma unroll
    for (int j = 0; j < 16; ++j) {
        int q = j * 256 + t;
        int slot = q & 63;
        int sp = (q >> 6) & 1;
        int rtl = (q >> 7) & 1;
        int k16 = q >> 8;
        int rowl = rtl * 32 + (slot & 31);
        int k = k16 * 16 + (slot >> 5) * 8;
        const float* p = &ls[rowl * 260 + k];
        f16x8 o;
        if (sp == 0) {
            #pragma unroll
            for (int i = 0; i < 8; ++i) o[i] = (_Float16)p[i];
        } else {
            #pragma unroll
            for (int i = 0; i < 8; ++i) {
                _Float16 hv = (_Float16)p[i];
                o[i] = (_Float16)((p[i] - (float)hv) * 4096.0f);
            }
        }
        int rt = h * 2 + rtl;
        size_t off = (((size_t)k16 * 4 + rt) * 2 + sp) * 1024 + (size_t)slot * 16;
        *reinterpret_cast<f16x8*>(dstTile + off) = o;
    }
}

// ---------------------------------------------------------------------------
// r12 main GEMM: fp16-split MFMA + per-column argmax, m201-style fine phases.
// 512 threads = 8 waves (4M x 2N), tile 256x128, per-wave 64x64 (dual acc =
// 128 VGPR). BK=16, 16 phases, ring-3 LDS (3 x 24KB = 72KB, 1 block/CU).
// Per phase: {vmcnt(3) counted-wait, ONE s_barrier, 8 ds_read_b128, issue 3
// global_load_lds for phase s+2 into buf[(s+2)%3] (freed: all waves passed
// the top-of-s barrier => done reading s-1 == same buffer), lgkmcnt(0),
// setprio(1), 12 MFMA, setprio(0)}. vmcnt never drains to 0 until the tail.
// 8 waves slip between barriers -> role diversity; A-traffic halved vs 128^2.
// ---------------------------------------------------------------------------
__global__ __launch_bounds__(512, 2) void gemm_argmax_p_kernel(
    const char* __restrict__ xT, const char* __restrict__ wT,
    u64* __restrict__ keys)
{
    __shared__ __align__(16) char lds[3][24576];   // [buf][A 16KB | B 8KB]
    __shared__ u64 smax[128];

    const int tid = threadIdx.x;
    const int lane = tid & 63;
    const int wid = tid >> 6;           // 0..7
    const int wm = wid >> 1;            // 0..3 (M), rowtiles wm*2, wm*2+1
    const int wn = wid & 1;             // 0..1 (N), coltiles wn*2, wn*2+1
    const int q  = blockIdx.x;          // 0..15 (256-row group)
    const int cy = blockIdx.y;          // 0..7  (128-col chunk)
    const int b  = blockIdx.z;
    const int p0 = q * 256;
    const int c0 = cy * 128;

    const char* aTile0 = xT + ((size_t)(b * 32 + q * 2)) * TILE_BYTES;
    const char* bChunk = wT + (size_t)cy * TILE_BYTES;

    // per-thread staging: 3 chunks c = wid*3 + i of 24 (A:0..15, B:16..23).
    // stage stride in source = 8192 B (k16 term of the chunk offset formula).
    const char* sSrc[3];
    int sDst[3];
    #pragma unroll
    for (int i = 0; i < 3; ++i) {
        int c = wid * 3 + i;
        if (c < 16) {
            int half = c >> 3, rt4 = (c >> 1) & 3, sp = c & 1;
            sSrc[i] = aTile0 + (size_t)half * TILE_BYTES
                      + (size_t)((rt4 * 2 + sp) << 10) + (size_t)lane * 16;
            sDst[i] = c << 10;
        } else {
            int d = c - 16;
            sSrc[i] = bChunk + (size_t)(d << 10) + (size_t)lane * 16;
            sDst[i] = 16384 + (d << 10);
        }
    }

    f32x16 zero;
    #pragma unroll
    for (int i = 0; i < 16; ++i) zero[i] = 0.f;
    f32x16 acc_hi[2][2], acc_lo[2][2];
    #pragma unroll
    for (int i = 0; i < 2; ++i)
        #pragma unroll
        for (int j = 0; j < 2; ++j) { acc_hi[i][j] = zero; acc_lo[i][j] = zero; }

    // compute-side LDS offsets (linear per chunk, lane*16 -> conflict-free)
    const int aOff0 = (((wm * 2 + 0) >> 2) << 13) + ((((wm * 2 + 0) & 3) * 2) << 10) + lane * 16;
    const int aOff1 = (((wm * 2 + 1) >> 2) << 13) + ((((wm * 2 + 1) & 3) * 2) << 10) + lane * 16;
    const int bOff0 = 16384 + (((wn * 2 + 0) * 2) << 10) + lane * 16;
    const int bOff1 = 16384 + (((wn * 2 + 1) * 2) << 10) + lane * 16;

    // prologue: stage 0 -> buf0, stage 1 -> buf1 (6 loads/thread in flight)
    #pragma unroll
    for (int i = 0; i < 3; ++i) async_load16(sSrc[i], &lds[0][sDst[i]]);
    #pragma unroll
    for (int i = 0; i < 3; ++i) async_load16(sSrc[i] + 8192, &lds[1][sDst[i]]);

    #pragma unroll
    for (int st = 0; st < 16; ++st) {
        const int buf = st % 3;
        // retire this stage's 3 loads; keep next stage's 3 in flight
        if (st < 15) asm volatile("s_waitcnt vmcnt(3)" ::: "memory");
        else         asm volatile("s_waitcnt vmcnt(0)" ::: "memory");
        __builtin_amdgcn_s_barrier();

        const char* L = &lds[buf][0];
        f16x8 a[2][2], bv[2][2];
        a[0][0] = *reinterpret_cast<const f16x8*>(L + aOff0);
        a[0][1] = *reinterpret_cast<const f16x8*>(L + aOff0 + 1024);
        a[1][0] = *reinterpret_cast<const f16x8*>(L + aOff1);
        a[1][1] = *reinterpret_cast<const f16x8*>(L + aOff1 + 1024);
        bv[0][0] = *reinterpret_cast<const f16x8*>(L + bOff0);
        bv[0][1] = *reinterpret_cast<const f16x8*>(L + bOff0 + 1024);
        bv[1][0] = *reinterpret_cast<const f16x8*>(L + bOff1);
        bv[1][1] = *reinterpret_cast<const f16x8*>(L + bOff1 + 1024);

        // issue stage st+2 into buf[(st+2)%3] == buffer of stage st-1 (freed:
        // every wave passed the top-of-st barrier, so st-1 fully consumed)
        if (st + 2 < 16) {
            const int nb = (st + 2) % 3;
            #pragma unroll
            for (int i = 0; i < 3; ++i)
                async_load16(sSrc[i] + (size_t)(st + 2) * 8192, &lds[nb][sDst[i]]);
        }

        asm volatile("s_waitcnt lgkmcnt(0)" ::: "memory");
        __builtin_amdgcn_s_setprio(1);
        #pragma unroll
        for (int rt = 0; rt < 2; ++rt)
            #pragma unroll
            for (int ct = 0; ct < 2; ++ct) {
                acc_hi[rt][ct] = __builtin_amdgcn_mfma_f32_32x32x16_f16(
                    a[rt][0], bv[ct][0], acc_hi[rt][ct], 0, 0, 0);
                acc_lo[rt][ct] = __builtin_amdgcn_mfma_f32_32x32x16_f16(
                    a[rt][0], bv[ct][1], acc_lo[rt][ct], 0, 0, 0);
                acc_lo[rt][ct] = __builtin_amdgcn_mfma_f32_32x32x16_f16(
                    a[rt][1], bv[ct][0], acc_lo[rt][ct], 0, 0, 0);
            }
        __builtin_amdgcn_s_setprio(0);
    }

    // ---- epilogue: per-column argmax over this block's 256 rows ----
    if (tid < 128) smax[tid] = 0ull;
    __syncthreads();

    #pragma unroll
    for (int ct = 0; ct < 2; ++ct) {
        u64 bk = 0ull;
        #pragma unroll
        for (int rt = 0; rt < 2; ++rt) {
            f32x16 h = acc_hi[rt][ct];
            f32x16 l = acc_lo[rt][ct];
            #pragma unroll
            for (int reg = 0; reg < 16; ++reg) {
                float v = fmaxf(h[reg] + l[reg] * (1.0f / 4096.0f), 0.f);
                int prow = p0 + (wm * 2 + rt) * 32 +
                           (reg & 3) + 8 * (reg >> 2) + 4 * (lane >> 5);
                u64 key = ((u64)__float_as_uint(v) << 32) |
                          (unsigned int)(0xFFFFFFFFu - (unsigned int)prow);
                bk = bk > key ? bk : key;
            }
        }
        u64 other = __shfl_xor(bk, 32, 64);
        bk = bk > other ? bk : other;
        if (lane < 32) {
            int col = (wn * 2 + ct) * 32 + (lane & 31);
            atomicMax(&smax[col], bk);
        }
    }
    __syncthreads();
    if (tid < 128) {
        atomicMax(&keys[(size_t)b * CC + c0 + tid], smax[tid]);
    }
}

// ---------------------------------------------------------------------------
// fallback (ws too small): in-kernel conversion version (round-2, verified)
// ---------------------------------------------------------------------------
__global__ __launch_bounds__(256, 2) void gemm_argmax_conv_kernel(
    const float* __restrict__ x, const float* __restrict__ W,
    u64* __restrict__ keys)
{
    __shared__ f16x8 lA[4][4][2][64];
    __shared__ f16x8 lB[4][4][2][64];

    const int tid = threadIdx.x;
    const int lane = tid & 63;
    const int w = tid >> 6;
    const int wy = w >> 1, wx = w & 1;
    const int p0 = blockIdx.x * 128;
    const int c0 = blockIdx.y * 128;
    const int b  = blockIdx.z;

    const float* xb = x + (size_t)b * PP * DD;

    f32x16 zero;
    #pragma unroll
    for (int i = 0; i < 16; ++i) zero[i] = 0.f;
    f32x16 acc_hi[2][2], acc_lo[2][2];
    #pragma unroll
    for (int i = 0; i < 2; ++i)
        #pragma unroll
        for (int j = 0; j < 2; ++j) { acc_hi[i][j] = zero; acc_lo[i][j] = zero; }

    for (int st = 0; st < 4; ++st) {
        const int k0 = st * 64;
        float4 gA[8], gB[8];
        #pragma unroll
        for (int v = 0; v < 4; ++v) {
            int pi = tid + 256 * v;
            int r  = pi >> 3;
            int ck = (pi & 7) * 8;
            const float* pa = xb + (size_t)(p0 + r) * DD + k0 + ck;
            gA[2 * v]     = *reinterpret_cast<const float4*>(pa);
            gA[2 * v + 1] = *reinterpret_cast<const float4*>(pa + 4);
            const float* pb = W + (size_t)(c0 + r) * DD + k0 + ck;
            gB[2 * v]     = *reinterpret_cast<const float4*>(pb);
            gB[2 * v + 1] = *reinterpret_cast<const float4*>(pb + 4);
        }
        __syncthreads();
        #pragma unroll
        for (int v = 0; v < 4; ++v) {
            int pi = tid + 256 * v;
            int r  = pi >> 3;
            int ph = pi & 7;
            int kk = ph >> 1;
            int half = ph & 1;
            int slot = (r & 31) + 32 * half;
            int rtp = r >> 5;
            float va[8] = {gA[2*v].x, gA[2*v].y, gA[2*v].z, gA[2*v].w,
                           gA[2*v+1].x, gA[2*v+1].y, gA[2*v+1].z, gA[2*v+1].w};
            f16x8 h1, h2;
            #pragma unroll
            for (int i = 0; i < 8; ++i) {
                _Float16 h = (_Float16)va[i];
                h1[i] = h;
                h2[i] = (_Float16)((va[i] - (float)h) * 4096.0f);
            }
            lA[kk][rtp][0][slot] = h1;
            lA[kk][rtp][1][slot] = h2;
            float vb[8] = {gB[2*v].x, gB[2*v].y, gB[2*v].z, gB[2*v].w,
                           gB[2*v+1].x, gB[2*v+1].y, gB[2*v+1].z, gB[2*v+1].w};
            f16x8 g1, g2;
            #pragma unroll
            for (int i = 0; i < 8; ++i) {
                _Float16 h = (_Float16)vb[i];
                g1[i] = h;
                g2[i] = (_Float16)((vb[i] - (float)h) * 4096.0f);
            }
            lB[kk][rtp][0][slot] = g1;
            lB[kk][rtp][1][slot] = g2;
        }
        __syncthreads();
        #pragma unroll
        for (int kk = 0; kk < 4; ++kk) {
            f16x8 xa[2][2], wb2[2][2];
            #pragma unroll
            for (int rt = 0; rt < 2; ++rt) {
                xa[rt][0] = lA[kk][wy * 2 + rt][0][lane];
                xa[rt][1] = lA[kk][wy * 2 + rt][1][lane];
            }
            #pragma unroll
            for (int ct = 0; ct < 2; ++ct) {
                wb2[ct][0] = lB[kk][wx * 2 + ct][0][lane];
                wb2[ct][1] = lB[kk][wx * 2 + ct][1][lane];
            }
            #pragma unroll
            for (int rt = 0; rt < 2; ++rt)
                #pragma unroll
                for (int ct = 0; ct < 2; ++ct) {
                    acc_hi[rt][ct] = __builtin_amdgcn_mfma_f32_32x32x16_f16(
                        xa[rt][0], wb2[ct][0], acc_hi[rt][ct], 0, 0, 0);
                    acc_lo[rt][ct] = __builtin_amdgcn_mfma_f32_32x32x16_f16(
                        xa[rt][0], wb2[ct][1], acc_lo[rt][ct], 0, 0, 0);
                    acc_lo[rt][ct] = __builtin_amdgcn_mfma_f32_32x32x16_f16(
                        xa[rt][1], wb2[ct][0], acc_lo[rt][ct], 0, 0, 0);
                }
        }
    }

    u64* smax = reinterpret_cast<u64*>(&lA[0][0][0][0]);
    __syncthreads();
    if (tid < 128) smax[tid] = 0ull;
    __syncthreads();

    #pragma unroll
    for (int ct = 0; ct < 2; ++ct) {
        u64 bk = 0ull;
        #pragma unroll
        for (int rt = 0; rt < 2; ++rt) {
            f32x16 h = acc_hi[rt][ct];
            f32x16 l = acc_lo[rt][ct];
            #pragma unroll
            for (int reg = 0; reg < 16; ++reg) {
                float v = fmaxf(h[reg] + l[reg] * (1.0f / 4096.0f), 0.f);
                int prow = p0 + (wy * 2 + rt) * 32 +
                           (reg & 3) + 8 * (reg >> 2) + 4 * (lane >> 5);
                u64 key = ((u64)__float_as_uint(v) << 32) |
                          (unsigned int)(0xFFFFFFFFu - (unsigned int)prow);
                bk = bk > key ? bk : key;
            }
        }
        u64 other = __shfl_xor(bk, 32, 64);
        bk = bk > other ? bk : other;
        if (lane < 32) {
            int col = (wx * 2 + ct) * 32 + (lane & 31);
            atomicMax(&smax[col], bk);
        }
    }
    __syncthreads();
    if (tid < 128) {
        atomicMax(&keys[(size_t)b * CC + c0 + tid], smax[tid]);
    }
}

// ---------------------------------------------------------------------------
// scatter: out[b, argmax_p(b,c), :] += W[c, :]
// ---------------------------------------------------------------------------
__global__ __launch_bounds__(64) void scatter_kernel(
    const u64* __restrict__ keys,
    const float* __restrict__ W,
    float* __restrict__ out)
{
    const int cell = blockIdx.x;
    const int c = cell & (CC - 1);
    const int b = cell >> 10;
    u64 key = keys[cell];
    unsigned int p = (0xFFFFFFFFu - (unsigned int)(key & 0xFFFFFFFFull)) & (PP - 1);

    const float* wrow = W + (size_t)c * DD;
    float* orow = out + ((size_t)b * PP + p) * DD;
    const int t = threadIdx.x;
    #pragma unroll
    for (int u = 0; u < 4; u++) {
        int idx = u * 64 + t;
        atomicAdd(&orow[idx], wrow[idx]);
    }
}

extern "C" void kernel_launch(void* const* d_in, const int* in_sizes, int n_in,
                              void* d_out, int out_size, void* d_ws, size_t ws_size,
                              hipStream_t stream) {
    const float* x = (const float*)d_in[0];   // [B, P, D] fp32
    const float* W = (const float*)d_in[1];   // [C, D]    fp32
    float* out = (float*)d_out;

    char* wsb = (char*)d_ws;
    u64* keys = (u64*)wsb;                          // 64 KB
    char* xT = wsb + 65536;
    char* wT = xT + XT_BYTES;
    const size_t need = 65536 + XT_BYTES + WT_BYTES;

    hipMemsetAsync(d_out, 0, (size_t)out_size * sizeof(float), stream);

    if (ws_size >= need) {
        transform_kernel<<<528, 256, 0, stream>>>(x, W, xT, wT, keys);
        dim3 grid(PP / 256, CC / 128, BB);
        gemm_argmax_p_kernel<<<grid, 512, 0, stream>>>(xT, wT, keys);
    } else {
        int n = BB * CC;
        init_ws_kernel<<<(n + 255) / 256, 256, 0, stream>>>(keys, n);
        dim3 grid(PP / 128, CC / 128, BB);
        gemm_argmax_conv_kernel<<<grid, 256, 0, stream>>>(x, W, keys);
    }

    {
        dim3 grid(BB * CC);
        scatter_kernel<<<grid, 64, 0, stream>>>(keys, W, out);
    }
}